// Round 7
// baseline (347.991 us; speedup 1.0000x reference)
//
#include <hip/hip_runtime.h>
#include <math.h>

#define B_   4
#define C_   256
#define G_   32
#define CPG  8                 // channels per group
#define N_   4096              // H*W
#define NPG  (CPG * N_)        // 32768 elements per group
#define EPS  1e-5f
#define SCALE 0.0625f          // C^-0.5 = 1/16

typedef __attribute__((ext_vector_type(8)))  __bf16 bf16x8;
typedef __attribute__((ext_vector_type(4)))  __bf16 bf16x4;
typedef __attribute__((ext_vector_type(16))) float  f32x16;

// ---------------------------------------------------------------------------
// Kernel 1a: GroupNorm stats. One block per (b,g): reduce 32768 floats ->
// mean, rstd written to stats[bg*2 .. +1].
// ---------------------------------------------------------------------------
__global__ __launch_bounds__(256) void gn_stats_kernel(const float* __restrict__ x,
                                                       float* __restrict__ stats) {
    int bg = blockIdx.x;                      // 0..127; groups are contiguous
    const float* xp = x + (size_t)bg * NPG;
    int tid = threadIdx.x;

    const float4* xp4 = (const float4*)xp;
    float s = 0.f, ss = 0.f;
    for (int i = tid; i < NPG / 4; i += 256) {
        float4 t = xp4[i];
        s  += t.x + t.y + t.z + t.w;
        ss += t.x * t.x + t.y * t.y + t.z * t.z + t.w * t.w;
    }
    #pragma unroll
    for (int off = 32; off; off >>= 1) {
        s  += __shfl_xor(s, off, 64);
        ss += __shfl_xor(ss, off, 64);
    }
    __shared__ float rs[2][4];
    int wave = tid >> 6, lane = tid & 63;
    if (lane == 0) { rs[0][wave] = s; rs[1][wave] = ss; }
    __syncthreads();
    if (tid == 0) {
        s  = rs[0][0] + rs[0][1] + rs[0][2] + rs[0][3];
        ss = rs[1][0] + rs[1][1] + rs[1][2] + rs[1][3];
        float mean = s / (float)NPG;
        float var  = ss / (float)NPG - mean * mean;
        stats[bg * 2]     = mean;
        stats[bg * 2 + 1] = rsqrtf(var + EPS);
    }
}

// ---------------------------------------------------------------------------
// Kernel 1b: GroupNorm apply. 2048 blocks (16 per group), bf16 frag-
// interleaved output [b][n>>5][c>>4][(c>>3)&1][n&31][c&7].
// ---------------------------------------------------------------------------
__global__ __launch_bounds__(256) void gn_apply_kernel(const float* __restrict__ x,
                                                       const float* __restrict__ w,
                                                       const float* __restrict__ bia,
                                                       const float* __restrict__ stats,
                                                       __bf16* __restrict__ xnb) {
    int bid = blockIdx.x;
    int bg = bid >> 4, seg = bid & 15;
    int b = bg >> 5, g = bg & 31;
    float mean = stats[bg * 2], rstd = stats[bg * 2 + 1];
    const float* xp = x + (size_t)bg * NPG;
    int n = seg * 256 + threadIdx.x;

    bf16x8 pk;
    #pragma unroll
    for (int cc = 0; cc < 8; cc++) {
        float sc = rstd * w[g * CPG + cc];
        float sh = bia[g * CPG + cc] - mean * sc;
        pk[cc] = (__bf16)(xp[(size_t)cc * N_ + n] * sc + sh);
    }
    size_t idx = ((((size_t)(b * 128 + (n >> 5)) * 16 + (g >> 1)) * 2 + (g & 1))
                  * 32 + (n & 31)) * 8;
    *(bf16x8*)(xnb + idx) = pk;
}

// ---------------------------------------------------------------------------
// Kernel 2: QKV projection, bf16 MFMA (unchanged from R5/R6).
// ---------------------------------------------------------------------------
__global__ __launch_bounds__(256) void qkv_kernel(const __bf16* __restrict__ xnb,
                                                  const float* __restrict__ W,
                                                  const float* __restrict__ bias,
                                                  __bf16* __restrict__ q,
                                                  __bf16* __restrict__ k,
                                                  __bf16* __restrict__ v) {
    int b = blockIdx.z, ot = blockIdx.y, nc = blockIdx.x;
    int tid = threadIdx.x, wv = tid >> 6, lane = tid & 63;
    int n31 = lane & 31, q2 = lane >> 5;
    int B0 = ot * 128 + wv * 32;

    bf16x8 wf[16];
    const float* wp = W + (size_t)(B0 + n31) * C_;
    #pragma unroll
    for (int ks = 0; ks < 16; ks++) {
        float4 t0 = *(const float4*)(wp + ks * 16 + q2 * 8);
        float4 t1 = *(const float4*)(wp + ks * 16 + q2 * 8 + 4);
        bf16x8 f;
        f[0] = (__bf16)t0.x; f[1] = (__bf16)t0.y; f[2] = (__bf16)t0.z; f[3] = (__bf16)t0.w;
        f[4] = (__bf16)t1.x; f[5] = (__bf16)t1.y; f[6] = (__bf16)t1.z; f[7] = (__bf16)t1.w;
        wf[ks] = f;
    }

    float bv[16], bvv = 0.f;
    if (ot < 4) {
        #pragma unroll
        for (int gI = 0; gI < 4; gI++)
            #pragma unroll
            for (int j = 0; j < 4; j++)
                bv[gI * 4 + j] = bias[B0 + gI * 8 + 4 * q2 + j];
    } else {
        bvv = bias[B0 + n31];
    }

    const __bf16* xb = xnb + (size_t)b * 128 * 8192;

    for (int t = 0; t < 4; t++) {
        int nt = nc * 4 + t;
        const __bf16* xg = xb + (size_t)nt * 8192 + q2 * 256 + n31 * 8;
        bf16x8 xf[16];
        #pragma unroll
        for (int ks = 0; ks < 16; ks++) xf[ks] = *(const bf16x8*)(xg + ks * 512);

        f32x16 acc;
        #pragma unroll
        for (int i = 0; i < 16; i++) acc[i] = 0.f;
        if (ot < 4) {
            #pragma unroll
            for (int ks = 0; ks < 16; ks++)
                acc = __builtin_amdgcn_mfma_f32_32x32x16_bf16(wf[ks], xf[ks], acc, 0, 0, 0);
        } else {
            #pragma unroll
            for (int ks = 0; ks < 16; ks++)
                acc = __builtin_amdgcn_mfma_f32_32x32x16_bf16(xf[ks], wf[ks], acc, 0, 0, 0);
        }

        if (ot < 4) {
            int ocb = (ot < 2) ? B0 : (B0 - 256);
            __bf16* dst = (ot < 2) ? q : k;
            bool isq = (ot < 2);
            #pragma unroll
            for (int gI = 0; gI < 4; gI++) {
                bf16x4 pk;
                #pragma unroll
                for (int j = 0; j < 4; j++) {
                    float y = acc[gI * 4 + j] + bv[gI * 4 + j];
                    if (isq) y *= SCALE;
                    pk[j] = (__bf16)y;
                }
                size_t idx = ((((size_t)(b * 128 + nt) * 16 + ((ocb >> 4) + (gI >> 1))) * 2
                               + (gI & 1)) * 32 + n31) * 8 + 4 * q2;
                *(bf16x4*)(dst + idx) = pk;
            }
        } else {
            int ocb = B0 - 512;
            #pragma unroll
            for (int gI = 0; gI < 4; gI++) {
                bf16x4 pk;
                #pragma unroll
                for (int j = 0; j < 4; j++)
                    pk[j] = (__bf16)(acc[gI * 4 + j] + bvv);
                size_t idx = (((((size_t)(b * 128 + nt) * 2 + (gI >> 1)) * 2 + (gI & 1)) * 8
                               + (ocb >> 5)) * 32 + n31) * 8 + 4 * q2;
                *(bf16x4*)(v + idx) = pk;
            }
        }
    }
}

// ---------------------------------------------------------------------------
// Kernel 3: MFMA attention with 2-way KEY SPLIT (partials are additive since
// there is no max-subtraction). 512 blocks = 4 b x 64 n-tiles x 2 splits ->
// 2 blocks/CU. Per block: 64 q-rows, keys [split*2048,+2048) in 16 chunks of
// 128. Phase A: S^T quarter (dual accumulator chains) -> exp -> bf16 P in
// dbuf LDS. Phase B: wave owns 32 chans, V-frags from global, P via LDS.
// Epilogue: fp32 partial O dump (register-native, coalesced) + l per split;
// merge + normalize happens in proj.
// ---------------------------------------------------------------------------
#define PS 132   // p_lds key stride in shorts

__global__ __launch_bounds__(512, 4) void attn_kernel(const __bf16* __restrict__ q,
                                                      const __bf16* __restrict__ k,
                                                      const __bf16* __restrict__ v,
                                                      float* __restrict__ ao0,
                                                      float* __restrict__ ao1,
                                                      float* __restrict__ l0,
                                                      float* __restrict__ l1) {
    __shared__ __bf16 p_lds[2 * 64 * PS];   // 33.8 KB
    __shared__ float l_lds[64];

    int bid   = blockIdx.x;
    int xcd   = bid & 7;
    int b     = xcd >> 1;
    int split = (bid >> 3) & 1;
    int n0    = (((bid >> 4) & 31) + (xcd & 1) * 32) * 64;

    int tid = threadIdx.x;
    int wid = tid >> 6, lane = tid & 63;
    int n31 = lane & 31, q2 = lane >> 5;
    int rt = wid & 1, kq = wid >> 1;        // phase-A role
    int rowA = rt * 32 + n31;

    if (tid < 64) l_lds[tid] = 0.f;

    // Q B-fragments for phase A (rows rt*32..+31): 64 VGPR, resident.
    const __bf16* qg = q + (((size_t)(b * 128 + (n0 >> 5) + rt) * 32 + q2) * 32 + n31) * 8;
    bf16x8 qf[16];
    #pragma unroll
    for (int ks = 0; ks < 16; ks++) qf[ks] = *(const bf16x8*)(qg + ks * 512);

    const size_t BSTR = (size_t)N_ * C_;
    const __bf16* kgb = k + (size_t)b * BSTR + ((size_t)q2 * 32 + n31) * 8;
    const __bf16* vgb = v + (size_t)b * BSTR + (size_t)q2 * 2048 + wid * 256 + n31 * 8;

    f32x16 o_acc[2];
    #pragma unroll
    for (int c = 0; c < 2; c++)
        #pragma unroll
        for (int i = 0; i < 16; i++) o_acc[c][i] = 0.f;
    float l_acc = 0.f;

    for (int ch = 0; ch < 16; ch++) {
        __bf16* pbuf = p_lds + (ch & 1) * (64 * PS);

        // ---- Phase A: S^T quarter, dual chains ----------------------------
        const __bf16* kg = kgb + (size_t)(split * 64 + ch * 4 + kq) * 8192;
        f32x16 s0, s1;
        #pragma unroll
        for (int i = 0; i < 16; i++) { s0[i] = 0.f; s1[i] = 0.f; }
        #pragma unroll
        for (int ks = 0; ks < 8; ks++) {
            bf16x8 ka = *(const bf16x8*)(kg + ks * 512);
            bf16x8 kb2 = *(const bf16x8*)(kg + (ks + 8) * 512);
            s0 = __builtin_amdgcn_mfma_f32_32x32x16_bf16(ka,  qf[ks],     s0, 0, 0, 0);
            s1 = __builtin_amdgcn_mfma_f32_32x32x16_bf16(kb2, qf[ks + 8], s1, 0, 0, 0);
        }
        #pragma unroll
        for (int g = 0; g < 4; g++) {
            bf16x4 pw;
            #pragma unroll
            for (int j = 0; j < 4; j++) {
                float p = __expf(s0[g * 4 + j] + s1[g * 4 + j]);
                l_acc += p;
                pw[j] = (__bf16)p;
            }
            *(bf16x4*)(pbuf + rowA * PS + kq * 32 + 8 * g + 4 * q2) = pw;
        }
        __syncthreads();

        // ---- Phase B: O^T[chan-tile wid][64 rows] over 128 keys -----------
        #pragma unroll
        for (int rtile = 0; rtile < 2; rtile++) {
            const __bf16* pb = pbuf + (rtile * 32 + n31) * PS + q2 * 8;
            #pragma unroll
            for (int kgrp = 0; kgrp < 8; kgrp++) {
                bf16x8 pf = *(const bf16x8*)(pb + kgrp * 16);
                bf16x8 vf = *(const bf16x8*)(vgb
                                + (size_t)(split * 64 + ch * 4 + (kgrp >> 1)) * 8192
                                + (kgrp & 1) * 4096);
                o_acc[rtile] = __builtin_amdgcn_mfma_f32_32x32x16_bf16(vf, pf, o_acc[rtile], 0, 0, 0);
            }
        }
    }

    atomicAdd(&l_lds[rowA], l_acc);
    __syncthreads();

    float* aop = split ? ao1 : ao0;
    float* lp  = split ? l1  : l0;
    if (tid < 64) lp[(size_t)b * N_ + n0 + tid] = l_lds[tid];

    // fp32 partial O dump: [b][nt64][wid][rtile][g][q2][n31][4] — coalesced.
    #pragma unroll
    for (int rtile = 0; rtile < 2; rtile++)
        #pragma unroll
        for (int g = 0; g < 4; g++) {
            float4 st;
            st.x = o_acc[rtile][g * 4 + 0];
            st.y = o_acc[rtile][g * 4 + 1];
            st.z = o_acc[rtile][g * 4 + 2];
            st.w = o_acc[rtile][g * 4 + 3];
            size_t idx = ((((((size_t)(b * 64 + (n0 >> 6)) * 8 + wid) * 2 + rtile) * 4 + g)
                           * 2 + q2) * 32 + n31) * 4;
            *(float4*)(aop + idx) = st;
        }
}

// ---------------------------------------------------------------------------
// Kernel 4: out projection. Merges the two attention partials, normalizes by
// l0+l1 while building B-frags, then bf16 MFMA + bias + residual -> fp32 out.
// ---------------------------------------------------------------------------
__global__ __launch_bounds__(256) void proj_kernel(const float* __restrict__ ao0,
                                                   const float* __restrict__ ao1,
                                                   const float* __restrict__ l0p,
                                                   const float* __restrict__ l1p,
                                                   const float* __restrict__ W2,
                                                   const float* __restrict__ bias,
                                                   const float* __restrict__ x,
                                                   float* __restrict__ out) {
    int b = blockIdx.z, ot = blockIdx.y, nc = blockIdx.x;
    int tid = threadIdx.x, wv = tid >> 6, lane = tid & 63;
    int n31 = lane & 31, q2 = lane >> 5;
    int B0 = ot * 128 + wv * 32;

    bf16x8 wf[16];
    const float* wp = W2 + (size_t)(B0 + n31) * C_;
    #pragma unroll
    for (int ks = 0; ks < 16; ks++) {
        float4 t0 = *(const float4*)(wp + ks * 16 + q2 * 8);
        float4 t1 = *(const float4*)(wp + ks * 16 + q2 * 8 + 4);
        bf16x8 f;
        f[0] = (__bf16)t0.x; f[1] = (__bf16)t0.y; f[2] = (__bf16)t0.z; f[3] = (__bf16)t0.w;
        f[4] = (__bf16)t1.x; f[5] = (__bf16)t1.y; f[6] = (__bf16)t1.z; f[7] = (__bf16)t1.w;
        wf[ks] = f;
    }
    float bv[16];
    #pragma unroll
    for (int r = 0; r < 16; r++) bv[r] = bias[B0 + (r & 3) + 8 * (r >> 2) + 4 * q2];

    for (int t = 0; t < 4; t++) {
        int nt = nc * 4 + t;                  // 32-row tile, 0..127
        int nt64 = nt >> 1, rtile = nt & 1;
        int n = nt * 32 + n31;
        float inv = 1.0f / (l0p[(size_t)b * N_ + n] + l1p[(size_t)b * N_ + n]);

        bf16x8 xf[16];
        #pragma unroll
        for (int ks = 0; ks < 16; ks++) {
            int oct = ks * 2 + q2;
            int wa = oct >> 2, ga = oct & 3;
            size_t base = ((((((size_t)(b * 64 + nt64) * 8 + wa) * 2 + rtile) * 4 + ga)
                            * 2) * 32 + n31) * 4;
            float4 a0 = *(const float4*)(ao0 + base);
            float4 b0 = *(const float4*)(ao0 + base + 128);
            float4 a1 = *(const float4*)(ao1 + base);
            float4 b1 = *(const float4*)(ao1 + base + 128);
            bf16x8 f;
            f[0] = (__bf16)((a0.x + a1.x) * inv);
            f[1] = (__bf16)((a0.y + a1.y) * inv);
            f[2] = (__bf16)((a0.z + a1.z) * inv);
            f[3] = (__bf16)((a0.w + a1.w) * inv);
            f[4] = (__bf16)((b0.x + b1.x) * inv);
            f[5] = (__bf16)((b0.y + b1.y) * inv);
            f[6] = (__bf16)((b0.z + b1.z) * inv);
            f[7] = (__bf16)((b0.w + b1.w) * inv);
            xf[ks] = f;
        }

        f32x16 acc;
        #pragma unroll
        for (int i = 0; i < 16; i++) acc[i] = 0.f;
        #pragma unroll
        for (int ks = 0; ks < 16; ks++)
            acc = __builtin_amdgcn_mfma_f32_32x32x16_bf16(wf[ks], xf[ks], acc, 0, 0, 0);

        #pragma unroll
        for (int r = 0; r < 16; r++) {
            int o = B0 + (r & 3) + 8 * (r >> 2) + 4 * q2;
            size_t idx = ((size_t)(b * C_ + o)) * N_ + nt * 32 + n31;
            out[idx] = acc[r] + bv[r] + x[idx];
        }
    }
}

// ---------------------------------------------------------------------------
extern "C" void kernel_launch(void* const* d_in, const int* in_sizes, int n_in,
                              void* d_out, int out_size, void* d_ws, size_t ws_size,
                              hipStream_t stream) {
    const float* x     = (const float*)d_in[0];
    const float* gn_w  = (const float*)d_in[1];
    const float* gn_b  = (const float*)d_in[2];
    const float* qkv_w = (const float*)d_in[3];
    const float* qkv_b = (const float*)d_in[4];
    const float* out_w = (const float*)d_in[5];
    const float* out_b = (const float*)d_in[6];
    float* out = (float*)d_out;

    const size_t SZ = (size_t)B_ * C_ * N_;       // 4,194,304 elements
    char* base = (char*)d_ws;
    float*  ao0 = (float*)base;                   // 16.78 MB fp32 partial O
    float*  ao1 = (float*)(base + SZ * 4);        // 16.78 MB
    __bf16* xnb = (__bf16*)base;                  // aliases ao0 (dead by attn)
    __bf16* qb  = (__bf16*)(base + 2 * SZ * 4);   // 8.39 MB each
    __bf16* kb  = qb + SZ;
    __bf16* vb  = kb + SZ;
    float*  l0  = (float*)(base + 2 * SZ * 4 + 3 * SZ * 2);  // [B,N] fp32
    float*  l1  = l0 + B_ * N_;
    float*  st  = l1 + B_ * N_;                   // [128][2] stats

    gn_stats_kernel<<<dim3(B_ * G_), 256, 0, stream>>>(x, st);
    gn_apply_kernel<<<dim3(2048), 256, 0, stream>>>(x, gn_w, gn_b, st, xnb);
    qkv_kernel<<<dim3(32, 6, B_), 256, 0, stream>>>(xnb, qkv_w, qkv_b, qb, kb, vb);
    attn_kernel<<<dim3(512), 512, 0, stream>>>(qb, kb, vb, ao0, ao1, l0, l1);
    proj_kernel<<<dim3(32, 2, B_), 256, 0, stream>>>(ao0, ao1, l0, l1, out_w, out_b, x, out);
}

// Round 8
// 292.487 us; speedup vs baseline: 1.1898x; 1.1898x over previous
//
#include <hip/hip_runtime.h>
#include <math.h>

#define B_   4
#define C_   256
#define G_   32
#define CPG  8                 // channels per group
#define N_   4096              // H*W
#define NPG  (CPG * N_)        // 32768 elements per group
#define EPS  1e-5f
#define SCALE 0.0625f          // C^-0.5 = 1/16

typedef __attribute__((ext_vector_type(8)))  __bf16 bf16x8;
typedef __attribute__((ext_vector_type(4)))  __bf16 bf16x4;
typedef __attribute__((ext_vector_type(16))) float  f32x16;

// ---------------------------------------------------------------------------
// Kernel 1a: GroupNorm partial sums. 512 blocks = 128 groups x 4 segments.
// part[bid] = {sum, sumsq} over 8192 floats.
// ---------------------------------------------------------------------------
__global__ __launch_bounds__(256) void gn_stats_kernel(const float* __restrict__ x,
                                                       float* __restrict__ part) {
    int bid = blockIdx.x;                 // bg*4 + seg
    int bg = bid >> 2, seg = bid & 3;
    const float4* xp4 = (const float4*)(x + (size_t)bg * NPG) + seg * 2048;
    int tid = threadIdx.x;

    float s = 0.f, ss = 0.f;
    for (int i = tid; i < 2048; i += 256) {
        float4 t = xp4[i];
        s  += t.x + t.y + t.z + t.w;
        ss += t.x * t.x + t.y * t.y + t.z * t.z + t.w * t.w;
    }
    #pragma unroll
    for (int off = 32; off; off >>= 1) {
        s  += __shfl_xor(s, off, 64);
        ss += __shfl_xor(ss, off, 64);
    }
    __shared__ float rs[2][4];
    int wave = tid >> 6, lane = tid & 63;
    if (lane == 0) { rs[0][wave] = s; rs[1][wave] = ss; }
    __syncthreads();
    if (tid == 0) {
        part[bid * 2]     = rs[0][0] + rs[0][1] + rs[0][2] + rs[0][3];
        part[bid * 2 + 1] = rs[1][0] + rs[1][1] + rs[1][2] + rs[1][3];
    }
}

// ---------------------------------------------------------------------------
// Kernel 1b: GroupNorm apply. 2048 blocks; combines the 4 partials inline,
// writes bf16 frag-interleaved [b][n>>5][c>>4][(c>>3)&1][n&31][c&7].
// ---------------------------------------------------------------------------
__global__ __launch_bounds__(256) void gn_apply_kernel(const float* __restrict__ x,
                                                       const float* __restrict__ w,
                                                       const float* __restrict__ bia,
                                                       const float* __restrict__ part,
                                                       __bf16* __restrict__ xnb) {
    int bid = blockIdx.x;
    int bg = bid >> 4, seg = bid & 15;
    int b = bg >> 5, g = bg & 31;
    float s  = part[(bg * 4 + 0) * 2] + part[(bg * 4 + 1) * 2]
             + part[(bg * 4 + 2) * 2] + part[(bg * 4 + 3) * 2];
    float ss = part[(bg * 4 + 0) * 2 + 1] + part[(bg * 4 + 1) * 2 + 1]
             + part[(bg * 4 + 2) * 2 + 1] + part[(bg * 4 + 3) * 2 + 1];
    float mean = s / (float)NPG;
    float var  = ss / (float)NPG - mean * mean;
    float rstd = rsqrtf(var + EPS);

    const float* xp = x + (size_t)bg * NPG;
    int n = seg * 256 + threadIdx.x;

    bf16x8 pk;
    #pragma unroll
    for (int cc = 0; cc < 8; cc++) {
        float sc = rstd * w[g * CPG + cc];
        float sh = bia[g * CPG + cc] - mean * sc;
        pk[cc] = (__bf16)(xp[(size_t)cc * N_ + n] * sc + sh);
    }
    size_t idx = ((((size_t)(b * 128 + (n >> 5)) * 16 + (g >> 1)) * 2 + (g & 1))
                  * 32 + (n & 31)) * 8;
    *(bf16x8*)(xnb + idx) = pk;
}

// ---------------------------------------------------------------------------
// Kernel 2: QKV projection, bf16 MFMA (unchanged from R5/R6).
// ---------------------------------------------------------------------------
__global__ __launch_bounds__(256) void qkv_kernel(const __bf16* __restrict__ xnb,
                                                  const float* __restrict__ W,
                                                  const float* __restrict__ bias,
                                                  __bf16* __restrict__ q,
                                                  __bf16* __restrict__ k,
                                                  __bf16* __restrict__ v) {
    int b = blockIdx.z, ot = blockIdx.y, nc = blockIdx.x;
    int tid = threadIdx.x, wv = tid >> 6, lane = tid & 63;
    int n31 = lane & 31, q2 = lane >> 5;
    int B0 = ot * 128 + wv * 32;

    bf16x8 wf[16];
    const float* wp = W + (size_t)(B0 + n31) * C_;
    #pragma unroll
    for (int ks = 0; ks < 16; ks++) {
        float4 t0 = *(const float4*)(wp + ks * 16 + q2 * 8);
        float4 t1 = *(const float4*)(wp + ks * 16 + q2 * 8 + 4);
        bf16x8 f;
        f[0] = (__bf16)t0.x; f[1] = (__bf16)t0.y; f[2] = (__bf16)t0.z; f[3] = (__bf16)t0.w;
        f[4] = (__bf16)t1.x; f[5] = (__bf16)t1.y; f[6] = (__bf16)t1.z; f[7] = (__bf16)t1.w;
        wf[ks] = f;
    }

    float bv[16], bvv = 0.f;
    if (ot < 4) {
        #pragma unroll
        for (int gI = 0; gI < 4; gI++)
            #pragma unroll
            for (int j = 0; j < 4; j++)
                bv[gI * 4 + j] = bias[B0 + gI * 8 + 4 * q2 + j];
    } else {
        bvv = bias[B0 + n31];
    }

    const __bf16* xb = xnb + (size_t)b * 128 * 8192;

    for (int t = 0; t < 4; t++) {
        int nt = nc * 4 + t;
        const __bf16* xg = xb + (size_t)nt * 8192 + q2 * 256 + n31 * 8;
        bf16x8 xf[16];
        #pragma unroll
        for (int ks = 0; ks < 16; ks++) xf[ks] = *(const bf16x8*)(xg + ks * 512);

        f32x16 acc;
        #pragma unroll
        for (int i = 0; i < 16; i++) acc[i] = 0.f;
        if (ot < 4) {
            #pragma unroll
            for (int ks = 0; ks < 16; ks++)
                acc = __builtin_amdgcn_mfma_f32_32x32x16_bf16(wf[ks], xf[ks], acc, 0, 0, 0);
        } else {
            #pragma unroll
            for (int ks = 0; ks < 16; ks++)
                acc = __builtin_amdgcn_mfma_f32_32x32x16_bf16(xf[ks], wf[ks], acc, 0, 0, 0);
        }

        if (ot < 4) {
            int ocb = (ot < 2) ? B0 : (B0 - 256);
            __bf16* dst = (ot < 2) ? q : k;
            bool isq = (ot < 2);
            #pragma unroll
            for (int gI = 0; gI < 4; gI++) {
                bf16x4 pk;
                #pragma unroll
                for (int j = 0; j < 4; j++) {
                    float y = acc[gI * 4 + j] + bv[gI * 4 + j];
                    if (isq) y *= SCALE;
                    pk[j] = (__bf16)y;
                }
                size_t idx = ((((size_t)(b * 128 + nt) * 16 + ((ocb >> 4) + (gI >> 1))) * 2
                               + (gI & 1)) * 32 + n31) * 8 + 4 * q2;
                *(bf16x4*)(dst + idx) = pk;
            }
        } else {
            int ocb = B0 - 512;
            #pragma unroll
            for (int gI = 0; gI < 4; gI++) {
                bf16x4 pk;
                #pragma unroll
                for (int j = 0; j < 4; j++)
                    pk[j] = (__bf16)(acc[gI * 4 + j] + bvv);
                size_t idx = (((((size_t)(b * 128 + nt) * 2 + (gI >> 1)) * 2 + (gI & 1)) * 8
                               + (ocb >> 5)) * 32 + n31) * 8 + 4 * q2;
                *(bf16x4*)(v + idx) = pk;
            }
        }
    }
}

// ---------------------------------------------------------------------------
// Kernel 3: MFMA attention. 256 blocks (1/CU), 512 thr = 8 waves, XCD swizzle.
// K chunks (128 keys x 256 ch = 64 KB) staged via global_load_lds into a
// DOUBLE-BUFFERED LDS (2x64 KB); phase A reads K-frags with ds_read_b128.
// V-frags register-prefetched at chunk top (latency covered by phase A).
// Phase A: S^T quarter -> exp -> bf16 P in LDS. Phase B: O^T chan-slice.
// Epilogue: normalize, bf16 ao frag-interleaved (R6 form).
// ---------------------------------------------------------------------------
#define PS 132   // p_lds key stride in shorts

__global__ __launch_bounds__(512, 2) void attn_kernel(const __bf16* __restrict__ q,
                                                      const __bf16* __restrict__ k,
                                                      const __bf16* __restrict__ v,
                                                      __bf16* __restrict__ ao) {
    __shared__ __bf16 k_lds[2][32768];      // 2 x 64 KB staged K chunks
    __shared__ __bf16 p_lds[64 * PS];       // 16.9 KB
    __shared__ float l_lds[64];

    int bid = blockIdx.x;
    int xcd = bid & 7;
    int b   = xcd >> 1;
    int n0  = ((bid >> 3) + (xcd & 1) * 32) * 64;

    int tid = threadIdx.x;
    int wid = tid >> 6, lane = tid & 63;
    int n31 = lane & 31, q2 = lane >> 5;
    int rt = wid & 1, kq = wid >> 1;        // phase-A role
    int rowA = rt * 32 + n31;

    if (tid < 64) l_lds[tid] = 0.f;

    // Q B-fragments for phase A (rows rt*32..+31): 64 VGPR, resident.
    const __bf16* qg = q + (((size_t)(b * 128 + (n0 >> 5) + rt) * 32 + q2) * 32 + n31) * 8;
    bf16x8 qf[16];
    #pragma unroll
    for (int ks = 0; ks < 16; ks++) qf[ks] = *(const bf16x8*)(qg + ks * 512);

    const size_t BSTR = (size_t)N_ * C_;
    const __bf16* kbase = k + (size_t)b * BSTR;   // chunk ch at +ch*32768
    const __bf16* vgb = v + (size_t)b * BSTR + (size_t)q2 * 2048 + wid * 256 + n31 * 8;

    // async K DMA: wave wid moves 8 KB (8 x 1 KB slices), lane x 16 B deposit.
    auto dma_k = [&](int ch, int buf) {
        const __bf16* src = kbase + (size_t)ch * 32768 + wid * 4096 + lane * 8;
        __bf16* dst = &k_lds[buf][wid * 4096];
        #pragma unroll
        for (int i = 0; i < 8; i++) {
            __builtin_amdgcn_global_load_lds(
                (const __attribute__((address_space(1))) void*)(src + i * 512),
                (__attribute__((address_space(3))) void*)(dst + i * 512), 16, 0, 0);
        }
    };

    f32x16 o_acc[2];
    #pragma unroll
    for (int c = 0; c < 2; c++)
        #pragma unroll
        for (int i = 0; i < 16; i++) o_acc[c][i] = 0.f;
    float l_acc = 0.f;

    dma_k(0, 0);

    for (int ch = 0; ch < 32; ch++) {
        int cur = ch & 1;
        __syncthreads();                    // buf[cur] staged; p_lds free
        if (ch + 1 < 32) dma_k(ch + 1, cur ^ 1);

        // ---- V register prefetch (8 frags, each used for both row-tiles) --
        bf16x8 vf[8];
        #pragma unroll
        for (int kg2 = 0; kg2 < 8; kg2++)
            vf[kg2] = *(const bf16x8*)(vgb + (size_t)(ch * 4 + (kg2 >> 1)) * 8192
                                       + (kg2 & 1) * 4096);

        // ---- Phase A: S^T quarter from LDS K, dual chains -----------------
        const __bf16* klds = &k_lds[cur][kq * 8192];
        f32x16 s0, s1;
        #pragma unroll
        for (int i = 0; i < 16; i++) { s0[i] = 0.f; s1[i] = 0.f; }
        #pragma unroll
        for (int ks = 0; ks < 8; ks++) {
            bf16x8 ka  = *(const bf16x8*)(klds + ks * 512 + lane * 8);
            bf16x8 kb2 = *(const bf16x8*)(klds + (ks + 8) * 512 + lane * 8);
            s0 = __builtin_amdgcn_mfma_f32_32x32x16_bf16(ka,  qf[ks],     s0, 0, 0, 0);
            s1 = __builtin_amdgcn_mfma_f32_32x32x16_bf16(kb2, qf[ks + 8], s1, 0, 0, 0);
        }
        #pragma unroll
        for (int g = 0; g < 4; g++) {
            bf16x4 pw;
            #pragma unroll
            for (int j = 0; j < 4; j++) {
                float p = __expf(s0[g * 4 + j] + s1[g * 4 + j]);
                l_acc += p;
                pw[j] = (__bf16)p;
            }
            *(bf16x4*)(p_lds + rowA * PS + kq * 32 + 8 * g + 4 * q2) = pw;
        }
        __syncthreads();                    // P ready

        // ---- Phase B: O^T[chan-tile wid][64 rows] over 128 keys -----------
        #pragma unroll
        for (int rtile = 0; rtile < 2; rtile++) {
            const __bf16* pb = p_lds + (rtile * 32 + n31) * PS + q2 * 8;
            #pragma unroll
            for (int kg2 = 0; kg2 < 8; kg2++) {
                bf16x8 pf = *(const bf16x8*)(pb + kg2 * 16);
                o_acc[rtile] = __builtin_amdgcn_mfma_f32_32x32x16_bf16(vf[kg2], pf, o_acc[rtile], 0, 0, 0);
            }
        }
    }

    // ---- l reduction -------------------------------------------------------
    atomicAdd(&l_lds[rowA], l_acc);
    __syncthreads();

    // ---- normalize + write ao bf16 frag-interleaved -----------------------
    #pragma unroll
    for (int rtile = 0; rtile < 2; rtile++) {
        float inv = 1.0f / l_lds[rtile * 32 + n31];
        int nt = (n0 >> 5) + rtile;
        #pragma unroll
        for (int g = 0; g < 4; g++) {
            bf16x4 pk;
            #pragma unroll
            for (int j = 0; j < 4; j++)
                pk[j] = (__bf16)(o_acc[rtile][g * 4 + j] * inv);
            size_t idx = ((((size_t)(b * 128 + nt) * 16 + wid * 2 + (g >> 1)) * 2
                           + (g & 1)) * 32 + n31) * 8 + 4 * q2;
            *(bf16x4*)(ao + idx) = pk;
        }
    }
}

// ---------------------------------------------------------------------------
// Kernel 4: out projection, bf16 MFMA + bias + residual (R6 version).
// ---------------------------------------------------------------------------
__global__ __launch_bounds__(256) void proj_kernel(const __bf16* __restrict__ ao,
                                                   const float* __restrict__ W2,
                                                   const float* __restrict__ bias,
                                                   const float* __restrict__ x,
                                                   float* __restrict__ out) {
    int b = blockIdx.z, ot = blockIdx.y, nc = blockIdx.x;
    int tid = threadIdx.x, wv = tid >> 6, lane = tid & 63;
    int n31 = lane & 31, q2 = lane >> 5;
    int B0 = ot * 128 + wv * 32;

    bf16x8 wf[16];
    const float* wp = W2 + (size_t)(B0 + n31) * C_;
    #pragma unroll
    for (int ks = 0; ks < 16; ks++) {
        float4 t0 = *(const float4*)(wp + ks * 16 + q2 * 8);
        float4 t1 = *(const float4*)(wp + ks * 16 + q2 * 8 + 4);
        bf16x8 f;
        f[0] = (__bf16)t0.x; f[1] = (__bf16)t0.y; f[2] = (__bf16)t0.z; f[3] = (__bf16)t0.w;
        f[4] = (__bf16)t1.x; f[5] = (__bf16)t1.y; f[6] = (__bf16)t1.z; f[7] = (__bf16)t1.w;
        wf[ks] = f;
    }
    float bv[16];
    #pragma unroll
    for (int r = 0; r < 16; r++) bv[r] = bias[B0 + (r & 3) + 8 * (r >> 2) + 4 * q2];

    const __bf16* ab = ao + (size_t)b * 128 * 8192;

    for (int t = 0; t < 4; t++) {
        int nt = nc * 4 + t;
        const __bf16* xg = ab + (size_t)nt * 8192 + q2 * 256 + n31 * 8;
        bf16x8 xf[16];
        #pragma unroll
        for (int ks = 0; ks < 16; ks++) xf[ks] = *(const bf16x8*)(xg + ks * 512);

        f32x16 acc;
        #pragma unroll
        for (int i = 0; i < 16; i++) acc[i] = 0.f;
        #pragma unroll
        for (int ks = 0; ks < 16; ks++)
            acc = __builtin_amdgcn_mfma_f32_32x32x16_bf16(wf[ks], xf[ks], acc, 0, 0, 0);

        #pragma unroll
        for (int r = 0; r < 16; r++) {
            int o = B0 + (r & 3) + 8 * (r >> 2) + 4 * q2;
            size_t idx = ((size_t)(b * C_ + o)) * N_ + nt * 32 + n31;
            out[idx] = acc[r] + bv[r] + x[idx];
        }
    }
}

// ---------------------------------------------------------------------------
extern "C" void kernel_launch(void* const* d_in, const int* in_sizes, int n_in,
                              void* d_out, int out_size, void* d_ws, size_t ws_size,
                              hipStream_t stream) {
    const float* x     = (const float*)d_in[0];
    const float* gn_w  = (const float*)d_in[1];
    const float* gn_b  = (const float*)d_in[2];
    const float* qkv_w = (const float*)d_in[3];
    const float* qkv_b = (const float*)d_in[4];
    const float* out_w = (const float*)d_in[5];
    const float* out_b = (const float*)d_in[6];
    float* out = (float*)d_out;

    const size_t SZ = (size_t)B_ * C_ * N_;   // 4,194,304 elements
    __bf16* xnb = (__bf16*)d_ws;              // frag-interleaved GN output
    __bf16* qb  = xnb + SZ;
    __bf16* kb  = qb + SZ;
    __bf16* vb  = kb + SZ;
    __bf16* aob = vb + SZ;                    // attn out, frag-interleaved
    float*  part = (float*)(aob + SZ);        // [512][2] GN partials

    gn_stats_kernel<<<dim3(512), 256, 0, stream>>>(x, part);
    gn_apply_kernel<<<dim3(2048), 256, 0, stream>>>(x, gn_w, gn_b, part, xnb);
    qkv_kernel<<<dim3(32, 6, B_), 256, 0, stream>>>(xnb, qkv_w, qkv_b, qb, kb, vb);
    attn_kernel<<<dim3(256), 512, 0, stream>>>(qb, kb, vb, aob);
    proj_kernel<<<dim3(32, 2, B_), 256, 0, stream>>>(aob, out_w, out_b, x, out);
}